// Round 1
// baseline (99.073 us; speedup 1.0000x reference)
//
#include <hip/hip_runtime.h>
#include <hip/hip_bf16.h>

// DynamicMaskHead (CondInst-style): per-instance 3-layer 1x1 conv MLP.
// Shapes fixed by the reference problem.
constexpr int N_IMG  = 2;
constexpr int IN_CH  = 8;
constexpr int CH     = 8;
constexpr int Himg   = 136;
constexpr int Wimg   = 200;
constexpr int HW     = Himg * Wimg;          // 27200
constexpr int N_INST = 128;
constexpr int NPAR   = 169;                  // 80+64+8 weights, 8+8+1 biases
constexpr int PX     = 8;                    // pixels per thread
constexpr int BLK    = 256;                  // threads per block
constexpr int PIX_PER_BLOCK = BLK * PX;      // 2048

// param offsets within the 169-float per-instance vector
constexpr int OFF_W0 = 0;    // (8,10)
constexpr int OFF_W1 = 80;   // (8,8)
constexpr int OFF_W2 = 144;  // (1,8)
constexpr int OFF_B0 = 152;  // (8)
constexpr int OFF_B1 = 160;  // (8)
constexpr int OFF_B2 = 168;  // (1)

__global__ __launch_bounds__(BLK)
void DynamicMaskHead_kernel(const float* __restrict__ mask_feats,   // (2,8,H,W)
                            const float* __restrict__ params,       // (128,169)
                            const float* __restrict__ inst_loc,     // (128,2)
                            const float* __restrict__ soi_table,    // (5,)
                            const int*   __restrict__ im_inds,      // (128,)
                            const int*   __restrict__ fpn_levels,   // (128,)
                            const int*   __restrict__ stride_ptr,   // (1,)
                            float*       __restrict__ out)          // (128,1,H,W)
{
    __shared__ float sp[NPAR];

    const int n = blockIdx.y;        // instance
    const int t = threadIdx.x;

    if (t < NPAR) sp[t] = params[n * NPAR + t];
    __syncthreads();

    const int   im      = im_inds[n];
    const float inv_soi = 1.0f / soi_table[fpn_levels[n]];
    const float ix      = inst_loc[2 * n + 0];
    const float iy      = inst_loc[2 * n + 1];
    const int   stride  = *stride_ptr;
    const float halfs   = (float)(stride / 2);

    const int p0 = (blockIdx.x * BLK + t) * PX;
    if (p0 >= HW) return;

    // ---- load features: f[c][j], coalesced float4 along pixels ----
    const float* fbase = mask_feats + (size_t)im * IN_CH * HW;
    float f[IN_CH][PX];
    const bool full = (p0 + PX <= HW);
#pragma unroll
    for (int c = 0; c < IN_CH; ++c) {
        const float* src = fbase + c * HW + p0;
        if (full) {
#pragma unroll
            for (int j = 0; j < PX; j += 4) {
                const float4 v = *reinterpret_cast<const float4*>(src + j);
                f[c][j + 0] = v.x; f[c][j + 1] = v.y;
                f[c][j + 2] = v.z; f[c][j + 3] = v.w;
            }
        } else {
#pragma unroll
            for (int j = 0; j < PX; ++j) {
                const int p = p0 + j;
                f[c][j] = (p < HW) ? src[j] : 0.0f;
            }
        }
    }

    // ---- relative coords per pixel ----
    float r0[PX], r1[PX];
#pragma unroll
    for (int j = 0; j < PX; ++j) {
        const int p  = p0 + j;
        const int py = p / Wimg;
        const int px = p - py * Wimg;
        r0[j] = (ix - (float)(px * stride) - halfs) * inv_soi;
        r1[j] = (iy - (float)(py * stride) - halfs) * inv_soi;
    }

    // ---- layer 0: (8 x 10) @ [r0, r1, f] + b0, relu ----
    float h[CH][PX];
#pragma unroll
    for (int o = 0; o < CH; ++o) {
        const float b  = sp[OFF_B0 + o];
        const float w0 = sp[OFF_W0 + o * 10 + 0];
        const float w1 = sp[OFF_W0 + o * 10 + 1];
#pragma unroll
        for (int j = 0; j < PX; ++j)
            h[o][j] = b + w0 * r0[j] + w1 * r1[j];
#pragma unroll
        for (int i = 0; i < IN_CH; ++i) {
            const float wv = sp[OFF_W0 + o * 10 + 2 + i];
#pragma unroll
            for (int j = 0; j < PX; ++j)
                h[o][j] = fmaf(wv, f[i][j], h[o][j]);
        }
#pragma unroll
        for (int j = 0; j < PX; ++j)
            h[o][j] = fmaxf(h[o][j], 0.0f);
    }

    // ---- layer 1: (8 x 8) @ h + b1, relu  (write into f, h still needed) ----
#pragma unroll
    for (int o = 0; o < CH; ++o) {
        const float b = sp[OFF_B1 + o];
        float acc[PX];
#pragma unroll
        for (int j = 0; j < PX; ++j) acc[j] = b;
#pragma unroll
        for (int i = 0; i < CH; ++i) {
            const float wv = sp[OFF_W1 + o * 8 + i];
#pragma unroll
            for (int j = 0; j < PX; ++j)
                acc[j] = fmaf(wv, h[i][j], acc[j]);
        }
#pragma unroll
        for (int j = 0; j < PX; ++j)
            f[o][j] = fmaxf(acc[j], 0.0f);
    }

    // ---- layer 2: (1 x 8) @ g + b2 ----
    float res[PX];
    const float b2 = sp[OFF_B2];
#pragma unroll
    for (int j = 0; j < PX; ++j) res[j] = b2;
#pragma unroll
    for (int i = 0; i < CH; ++i) {
        const float wv = sp[OFF_W2 + i];
#pragma unroll
        for (int j = 0; j < PX; ++j)
            res[j] = fmaf(wv, f[i][j], res[j]);
    }

    // ---- store ----
    float* obase = out + (size_t)n * HW + p0;
    if (full) {
#pragma unroll
        for (int j = 0; j < PX; j += 4) {
            *reinterpret_cast<float4*>(obase + j) =
                make_float4(res[j], res[j + 1], res[j + 2], res[j + 3]);
        }
    } else {
#pragma unroll
        for (int j = 0; j < PX; ++j) {
            if (p0 + j < HW) obase[j] = res[j];
        }
    }
}

extern "C" void kernel_launch(void* const* d_in, const int* in_sizes, int n_in,
                              void* d_out, int out_size, void* d_ws, size_t ws_size,
                              hipStream_t stream) {
    const float* mask_feats = (const float*)d_in[0];
    const float* params     = (const float*)d_in[1];
    const float* inst_loc   = (const float*)d_in[2];
    const float* soi_table  = (const float*)d_in[3];
    const int*   im_inds    = (const int*)d_in[4];
    const int*   fpn_levels = (const int*)d_in[5];
    const int*   stride_ptr = (const int*)d_in[6];
    float*       out        = (float*)d_out;

    const int blocks_x = (HW + PIX_PER_BLOCK - 1) / PIX_PER_BLOCK;  // 14
    dim3 grid(blocks_x, N_INST);
    dim3 block(BLK);
    hipLaunchKernelGGL(DynamicMaskHead_kernel, grid, block, 0, stream,
                       mask_feats, params, inst_loc, soi_table,
                       im_inds, fpn_levels, stride_ptr, out);
}

// Round 3
// 88.133 us; speedup vs baseline: 1.1241x; 1.1241x over previous
//
#include <hip/hip_runtime.h>
#include <hip/hip_bf16.h>

// DynamicMaskHead (CondInst-style): per-instance 3-layer 1x1-conv MLP.
// Key changes vs R1:
//  - NO LDS: per-instance params are block-uniform (n = blockIdx.y), so plain
//    global reads with uniform addresses compile to s_load (scalar cache) and
//    feed v_fmac as SGPR operands. Removes ~170 ds_read/thread + barrier.
//  - 8-aligned pixel chunks never cross a row (200 % 8 == 0): one int-div per
//    thread, r1 (y-coord) is scalar, r0[j] linear in j.
//  - No tail path (27200 % 8 == 0).
// (Resubmitted unchanged: R2 bench failed with GPUAcquisitionTimeout.)

constexpr int IN_CH  = 8;
constexpr int CH     = 8;
constexpr int Himg   = 136;
constexpr int Wimg   = 200;
constexpr int HW     = Himg * Wimg;          // 27200
constexpr int N_INST = 128;
constexpr int NPAR   = 169;
constexpr int PX     = 8;                    // pixels per thread (one row segment)
constexpr int BLK    = 256;
constexpr int PPB    = BLK * PX;             // 2048 pixels per block

constexpr int OFF_W0 = 0;    // (8,10)
constexpr int OFF_W1 = 80;   // (8,8)
constexpr int OFF_W2 = 144;  // (1,8)
constexpr int OFF_B0 = 152;  // (8)
constexpr int OFF_B1 = 160;  // (8)
constexpr int OFF_B2 = 168;  // (1)

__global__ __launch_bounds__(BLK)
void DynamicMaskHead_kernel(const float* __restrict__ mask_feats,   // (2,8,H,W)
                            const float* __restrict__ params,       // (128,169)
                            const float* __restrict__ inst_loc,     // (128,2)
                            const float* __restrict__ soi_table,    // (5,)
                            const int*   __restrict__ im_inds,      // (128,)
                            const int*   __restrict__ fpn_levels,   // (128,)
                            const int*   __restrict__ stride_ptr,   // (1,)
                            float*       __restrict__ out)          // (128,1,H,W)
{
    const int n = blockIdx.y;                       // instance (uniform)
    const float* __restrict__ pp = params + n * NPAR;  // uniform base -> s_loads

    const int p0 = blockIdx.x * PPB + threadIdx.x * PX;
    if (p0 >= HW) return;                           // whole-thread in/out (HW%8==0)

    // uniform scalars
    const int   im      = im_inds[n];
    const float inv_soi = 1.0f / soi_table[fpn_levels[n]];
    const float ix      = inst_loc[2 * n + 0];
    const float iy      = inst_loc[2 * n + 1];
    const int   stride  = *stride_ptr;
    const float halfs   = (float)(stride / 2);

    // coordinates: all 8 pixels share one row (Wimg % PX == 0)
    const int py  = p0 / Wimg;
    const int px0 = p0 - py * Wimg;
    const float d     = (float)stride * inv_soi;                       // step in x
    const float r0b   = (ix - (float)(px0 * stride) - halfs) * inv_soi;
    const float r1v   = (iy - (float)(py  * stride) - halfs) * inv_soi;
    float r0[PX];
#pragma unroll
    for (int j = 0; j < PX; ++j) r0[j] = r0b - (float)j * d;

    // ---- features: f[c][j], two float4 per channel, coalesced ----
    const float* fbase = mask_feats + (size_t)im * (IN_CH * HW) + p0;
    float f[IN_CH][PX];
#pragma unroll
    for (int c = 0; c < IN_CH; ++c) {
        const float4 v0 = *reinterpret_cast<const float4*>(fbase + c * HW);
        const float4 v1 = *reinterpret_cast<const float4*>(fbase + c * HW + 4);
        f[c][0] = v0.x; f[c][1] = v0.y; f[c][2] = v0.z; f[c][3] = v0.w;
        f[c][4] = v1.x; f[c][5] = v1.y; f[c][6] = v1.z; f[c][7] = v1.w;
    }

    // ---- layer 0: (8 x 10) @ [r0, r1, feats] + b0, relu ----
    float h[CH][PX];
#pragma unroll
    for (int o = 0; o < CH; ++o) {
        const float w0 = pp[OFF_W0 + o * 10 + 0];          // s_load -> SGPR
        const float w1 = pp[OFF_W0 + o * 10 + 1];
        const float bi = fmaf(w1, r1v, pp[OFF_B0 + o]);    // per-thread scalar
#pragma unroll
        for (int j = 0; j < PX; ++j)
            h[o][j] = fmaf(w0, r0[j], bi);
#pragma unroll
        for (int i = 0; i < IN_CH; ++i) {
            const float wv = pp[OFF_W0 + o * 10 + 2 + i];
#pragma unroll
            for (int j = 0; j < PX; ++j)
                h[o][j] = fmaf(wv, f[i][j], h[o][j]);
        }
#pragma unroll
        for (int j = 0; j < PX; ++j)
            h[o][j] = fmaxf(h[o][j], 0.0f);
    }

    // ---- layer 1: (8 x 8) @ h + b1, relu (overwrite f; features dead) ----
#pragma unroll
    for (int o = 0; o < CH; ++o) {
        const float b = pp[OFF_B1 + o];
        float acc[PX];
#pragma unroll
        for (int j = 0; j < PX; ++j) acc[j] = b;
#pragma unroll
        for (int i = 0; i < CH; ++i) {
            const float wv = pp[OFF_W1 + o * 8 + i];
#pragma unroll
            for (int j = 0; j < PX; ++j)
                acc[j] = fmaf(wv, h[i][j], acc[j]);
        }
#pragma unroll
        for (int j = 0; j < PX; ++j)
            f[o][j] = fmaxf(acc[j], 0.0f);
    }

    // ---- layer 2: (1 x 8) + b2 ----
    float res[PX];
    const float b2 = pp[OFF_B2];
#pragma unroll
    for (int j = 0; j < PX; ++j) res[j] = b2;
#pragma unroll
    for (int i = 0; i < CH; ++i) {
        const float wv = pp[OFF_W2 + i];
#pragma unroll
        for (int j = 0; j < PX; ++j)
            res[j] = fmaf(wv, f[i][j], res[j]);
    }

    // ---- store: two float4 ----
    float* obase = out + (size_t)n * HW + p0;
    *reinterpret_cast<float4*>(obase)     = make_float4(res[0], res[1], res[2], res[3]);
    *reinterpret_cast<float4*>(obase + 4) = make_float4(res[4], res[5], res[6], res[7]);
}

extern "C" void kernel_launch(void* const* d_in, const int* in_sizes, int n_in,
                              void* d_out, int out_size, void* d_ws, size_t ws_size,
                              hipStream_t stream) {
    const float* mask_feats = (const float*)d_in[0];
    const float* params     = (const float*)d_in[1];
    const float* inst_loc   = (const float*)d_in[2];
    const float* soi_table  = (const float*)d_in[3];
    const int*   im_inds    = (const int*)d_in[4];
    const int*   fpn_levels = (const int*)d_in[5];
    const int*   stride_ptr = (const int*)d_in[6];
    float*       out        = (float*)d_out;

    const int blocks_x = (HW + PPB - 1) / PPB;   // 14
    dim3 grid(blocks_x, N_INST);
    dim3 block(BLK);
    hipLaunchKernelGGL(DynamicMaskHead_kernel, grid, block, 0, stream,
                       mask_feats, params, inst_loc, soi_table,
                       im_inds, fpn_levels, stride_ptr, out);
}